// Round 3
// baseline (122.521 us; speedup 1.0000x reference)
//
#include <hip/hip_runtime.h>
#include <math.h>

// Additive (Bahdanau) attention. N=4, NQ=256, NV=512, NE=256, fp32.
// R3: split into high-occupancy logits kernel (trans-bound) + small epilogue kernel.
#define N_B   4
#define NQ_   256
#define NV_   512
#define NE_   256

// 2*log2(e): pre-scale q,c so sigma-term = rcp(1 + exp2(qs+cs))
#define QSCALE 2.8853900817779268f

__device__ __forceinline__ float wave_reduce_sum(float v) {
#pragma unroll
    for (int m = 32; m > 0; m >>= 1) v += __shfl_xor(v, m, 64);
    return v;
}

// ---- prep: C[n][v][e] -> CT[n][e][v], scaled by QSCALE ----
__global__ __launch_bounds__(256) void transpose_C(const float* __restrict__ C,
                                                   float* __restrict__ CT) {
    __shared__ float tile[64][65];
    const int n = blockIdx.z, v0 = blockIdx.x * 64, e0 = blockIdx.y * 64;
    const int col = threadIdx.x & 63, row4 = threadIdx.x >> 6;
    const float* src = C + ((size_t)n * NV_ + v0) * NE_ + e0;
#pragma unroll
    for (int r = 0; r < 16; ++r) {
        const int vl = row4 + r * 4;
        tile[vl][col] = src[(size_t)vl * NE_ + col] * QSCALE;
    }
    __syncthreads();
    float* dst = CT + ((size_t)n * NE_ + e0) * NV_ + v0;
#pragma unroll
    for (int r = 0; r < 16; ++r) {
        const int el = row4 + r * 4;
        dst[(size_t)el * NV_ + col] = tile[col][el];
    }
}

// ---- prep: WR[e'][e] -> WRT[e][e'] ----
__global__ __launch_bounds__(256) void transpose_W(const float* __restrict__ W,
                                                   float* __restrict__ WT) {
    __shared__ float tile[64][65];
    const int r0 = blockIdx.x * 64, c0 = blockIdx.y * 64;
    const int col = threadIdx.x & 63, row4 = threadIdx.x >> 6;
    const float* src = W + (size_t)r0 * NE_ + c0;
#pragma unroll
    for (int r = 0; r < 16; ++r) {
        const int rl = row4 + r * 4;
        tile[rl][col] = src[(size_t)rl * NE_ + col];
    }
    __syncthreads();
    float* dst = WT + (size_t)c0 * NE_ + r0;
#pragma unroll
    for (int r = 0; r < 16; ++r) {
        const int cl = row4 + r * 4;
        dst[(size_t)cl * NE_ + col] = tile[col][cl];
    }
}

// ---- kernel A: S[n][q][v] = sum_e w[e] * rcp(1+exp2(qs+cs)) ----
// block: 4 q-rows x 64 v; 4 waves split the e-range (64 e each).
// grid: (NV/64, NQ/4, N) = 2048 blocks -> 8 blocks/CU -> 100% occupancy.
#define QTA 4
__global__ __launch_bounds__(256, 8) void logits_kernel(
    const float* __restrict__ Q,   // [N][NQ][NE]
    const float* __restrict__ CT,  // [N][NE][NV] (pre-scaled)
    const float* __restrict__ WL,  // [NE]
    float* __restrict__ S)         // [N][NQ][NV]
{
    const int n  = blockIdx.z;
    const int q0 = blockIdx.y * QTA;
    const int v0 = blockIdx.x * 64;
    const int tid = threadIdx.x;
    const int wv = tid >> 6, ln = tid & 63;

    __shared__ __align__(16) float s_q[NE_][QTA];     // 4 KB
    __shared__ float s_w[NE_];                        // 1 KB
    __shared__ float s_part[4][QTA][64];              // 4 KB

    {   // preload q rows (scaled) + w_logit; thread == e
        const int e = tid;
        s_w[e] = WL[e];
#pragma unroll
        for (int j = 0; j < QTA; ++j)
            s_q[e][j] = Q[((size_t)n * NQ_ + q0 + j) * NE_ + e] * QSCALE;
    }
    __syncthreads();

    const float* ct = CT + (size_t)n * NE_ * NV_ + v0 + ln;
    float acc0 = 0.f, acc1 = 0.f, acc2 = 0.f, acc3 = 0.f;
    const int e0 = wv * 64;
#pragma unroll 4
    for (int e = e0; e < e0 + 64; ++e) {
        const float c = ct[(size_t)e * NV_];
        const float4 q4 = *(const float4*)s_q[e];
        const float w = s_w[e];
        acc0 = fmaf(w, __builtin_amdgcn_rcpf(1.0f + __builtin_amdgcn_exp2f(c + q4.x)), acc0);
        acc1 = fmaf(w, __builtin_amdgcn_rcpf(1.0f + __builtin_amdgcn_exp2f(c + q4.y)), acc1);
        acc2 = fmaf(w, __builtin_amdgcn_rcpf(1.0f + __builtin_amdgcn_exp2f(c + q4.z)), acc2);
        acc3 = fmaf(w, __builtin_amdgcn_rcpf(1.0f + __builtin_amdgcn_exp2f(c + q4.w)), acc3);
    }
    s_part[wv][0][ln] = acc0;
    s_part[wv][1][ln] = acc1;
    s_part[wv][2][ln] = acc2;
    s_part[wv][3][ln] = acc3;
    __syncthreads();

    {   // 4-way reduce + store; thread covers (j = tid>>6, lane = tid&63)
        const int j = tid >> 6, l = tid & 63;
        const float s = s_part[0][j][l] + s_part[1][j][l]
                      + s_part[2][j][l] + s_part[3][j][l];
        S[((size_t)n * NQ_ + q0 + j) * NV_ + v0 + l] = s;
    }
}

// ---- kernel B: softmax + PV + leaky_relu + output GEMM; block = (n, 2 q-rows) ----
#define QTB 2
__global__ __launch_bounds__(256) void attn_out(
    const float* __restrict__ S,     // [N][NQ][NV]
    const float* __restrict__ M,     // [N][NV][NE]
    const float* __restrict__ TEMP,
    const float* __restrict__ WRT,   // [NE][NE] = WR^T
    const float* __restrict__ BR,
    float* __restrict__ OUT)         // [N][NQ][NE]
{
    const int n  = blockIdx.y;
    const int q0 = blockIdx.x * QTB;
    const int tid = threadIdx.x;
    const int wv = tid >> 6, ln = tid & 63;

    __shared__ __align__(16) float s_prob[QTB][NV_];      // 4 KB
    __shared__ __align__(16) float s_part[4][QTB][NE_];   // 8 KB
    __shared__ __align__(16) float s_heads[QTB][NE_];     // 2 KB

    // softmax over v: wave 0 -> q0, wave 1 -> q0+1 (logit = -2*S/temp)
    if (wv < QTB) {
        const float scale = -2.0f / TEMP[0];
        const float* srow = S + ((size_t)n * NQ_ + q0 + wv) * NV_;
        float l[NV_ / 64];
        float mx = -1e30f;
#pragma unroll
        for (int k = 0; k < NV_ / 64; ++k) {
            l[k] = srow[ln + 64 * k] * scale;
            mx = fmaxf(mx, l[k]);
        }
#pragma unroll
        for (int m = 32; m > 0; m >>= 1) mx = fmaxf(mx, __shfl_xor(mx, m, 64));
        float sum = 0.0f;
#pragma unroll
        for (int k = 0; k < NV_ / 64; ++k) {
            l[k] = __expf(l[k] - mx);
            sum += l[k];
        }
        sum = wave_reduce_sum(sum);
        const float inv = 1.0f / sum;
#pragma unroll
        for (int k = 0; k < NV_ / 64; ++k) s_prob[wv][ln + 64 * k] = l[k] * inv;
    }
    __syncthreads();

    // PV: waves partition v (128 each); lane = float4 of e
    {
        const float4* M4 = (const float4*)(M + (size_t)n * NV_ * NE_);
        float4 h0 = make_float4(0.f, 0.f, 0.f, 0.f);
        float4 h1 = make_float4(0.f, 0.f, 0.f, 0.f);
        const int v0 = wv * (NV_ / 4);
#pragma unroll 4
        for (int v = v0; v < v0 + NV_ / 4; ++v) {
            const float4 m = M4[v * (NE_ / 4) + ln];
            const float p0 = s_prob[0][v];
            const float p1 = s_prob[1][v];
            h0.x = fmaf(p0, m.x, h0.x); h0.y = fmaf(p0, m.y, h0.y);
            h0.z = fmaf(p0, m.z, h0.z); h0.w = fmaf(p0, m.w, h0.w);
            h1.x = fmaf(p1, m.x, h1.x); h1.y = fmaf(p1, m.y, h1.y);
            h1.z = fmaf(p1, m.z, h1.z); h1.w = fmaf(p1, m.w, h1.w);
        }
        ((float4*)s_part[wv][0])[ln] = h0;
        ((float4*)s_part[wv][1])[ln] = h1;
    }
    __syncthreads();

    // reduce 4 wave-partials + leaky_relu
#pragma unroll
    for (int i = tid; i < QTB * NE_; i += 256) {
        const int t = i >> 8, e = i & (NE_ - 1);
        const float s = s_part[0][t][e] + s_part[1][t][e]
                      + s_part[2][t][e] + s_part[3][t][e];
        s_heads[t][e] = (s > 0.0f) ? s : 0.01f * s;
    }
    __syncthreads();

    // out[t][ep] = sum_e h[t][e]*WRT[e][ep] + BR[ep]; thread = ep (coalesced)
    {
        const float* w = WRT + tid;
        float a0 = 0.f, a1 = 0.f;
#pragma unroll 8
        for (int e = 0; e < NE_; ++e) {
            const float wv_ = w[(size_t)e * NE_];
            a0 = fmaf(s_heads[0][e], wv_, a0);
            a1 = fmaf(s_heads[1][e], wv_, a1);
        }
        const float b = BR[tid];
        OUT[((size_t)n * NQ_ + q0) * NE_ + tid]     = a0 + b;
        OUT[((size_t)n * NQ_ + q0 + 1) * NE_ + tid] = a1 + b;
    }
}

extern "C" void kernel_launch(void* const* d_in, const int* in_sizes, int n_in,
                              void* d_out, int out_size, void* d_ws, size_t ws_size,
                              hipStream_t stream) {
    const float* Q  = (const float*)d_in[0];
    const float* C  = (const float*)d_in[1];
    const float* M  = (const float*)d_in[2];
    const float* WL = (const float*)d_in[3];
    // d_in[4] = b_logit: softmax shift-invariant -> unused.
    const float* T  = (const float*)d_in[5];
    const float* WR = (const float*)d_in[6];
    const float* BR = (const float*)d_in[7];
    float* OUT = (float*)d_out;

    float* CT  = (float*)d_ws;                        // N*NE*NV = 524288 floats
    float* WRT = CT + (size_t)N_B * NE_ * NV_;        // NE*NE   = 65536 floats
    float* S   = WRT + (size_t)NE_ * NE_;             // N*NQ*NV = 524288 floats
    // total ws: ~4.5 MB

    dim3 gtc(NV_ / 64, NE_ / 64, N_B);
    transpose_C<<<gtc, 256, 0, stream>>>(C, CT);
    dim3 gtw(NE_ / 64, NE_ / 64);
    transpose_W<<<gtw, 256, 0, stream>>>(WR, WRT);

    dim3 ga(NV_ / 64, NQ_ / QTA, N_B);
    logits_kernel<<<ga, 256, 0, stream>>>(Q, CT, WL, S);

    dim3 gb(NQ_ / QTB, N_B);
    attn_out<<<gb, 256, 0, stream>>>(S, M, T, WRT, BR, OUT);
}